// Round 8
// baseline (39.373 us; speedup 1.0000x reference)
//
#include <hip/hip_runtime.h>

// LIF scan, x (B=32,G=4,T=512,C=256) f32 -> 32768 chains, T sequential.
// Memory-bound: 67 MB R + 67 MB W.
//
// R8 = R7's burst-alternation structure + transposed x4 store bursts + WIN 32.
//  - Block = sequence n (256 threads, 4 waves), 128 blocks.
//  - Reads: 32 KiB contiguous window bursts via 8x global_load_lds_dwordx4
//    per wave, triple-buffered (96 KiB LDS), 2 windows ahead, counted vmcnt
//    (never drained to 0), raw s_barrier only.
//  - Compute: 32 steps; xt via stride-1 ds_read (conflict-free); Vm chain in
//    registers; Vm written to obuf[k][ch] (stride-1 ds_write, conflict-free).
//  - Stores: after LDS barrier, wave wv stores rows 4i+wv as ONE contiguous
//    1 KiB global_store_dwordx4 each (ds_read_b128 at lane*16B, conflict-free)
//    -> block-instruction = 4 KiB contiguous (vs R7's 256 B wave-pieces).
//  - Recurrence bit-exact: contract off, v=(w*xt)+(a*Vm); Vm'=(Vm>=1)?0:v.

typedef float f32x4 __attribute__((ext_vector_type(4)));

constexpr int T_STEPS = 512;
constexpr int CCH     = 256;
constexpr int NSEQ    = 128;
constexpr int WIN     = 32;
constexpr int NWIN    = T_STEPS / WIN;   // 16

__device__ __forceinline__ void sfence() { __builtin_amdgcn_sched_barrier(0); }

__global__ __launch_bounds__(256, 1) void lif_kernel(
    const float* __restrict__ x,
    const float* __restrict__ w_input,
    const float* __restrict__ w_leak,
    float* __restrict__ out)
{
#pragma clang fp contract(off)
    __shared__ float xw[3][WIN * CCH];   // 3 x 32 KiB x-windows
    __shared__ float obuf[WIN * CCH];    // 32 KiB out staging

    const int tid = threadIdx.x;
    const int wv  = tid >> 6;
    const int l   = tid & 63;
    const int n   = blockIdx.x;

    const float w = w_input[tid];
    const float a = 1.0f - w_leak[tid];

    const float* xg = x   + (size_t)n * T_STEPS * CCH;
    float*       og = out + (size_t)n * T_STEPS * CCH;

    // 32 KiB read burst for window Wt into buffer Wt%3 (identity mapping:
    // wave wv, call i, lane l -> byte wv*1024 + i*4096 + l*16 on both sides).
    auto issue = [&](int Wt) {
        float* dst0 = &xw[Wt % 3][wv * 256];
        const float* src0 = xg + (size_t)Wt * (WIN * CCH) + tid * 4;
#pragma unroll
        for (int i = 0; i < 8; ++i) {
            __builtin_amdgcn_global_load_lds(
                (const __attribute__((address_space(1))) void*)(src0 + i * 1024),
                (__attribute__((address_space(3))) void*)(dst0 + i * 1024),
                16, 0, 0);
        }
        sfence();
    };

    float Vm = 0.0f;

    auto compute = [&](int Wt) {
        const float* xb = &xw[Wt % 3][0];
#pragma unroll
        for (int k = 0; k < WIN; ++k) {
            const float xt = xb[k * CCH + tid];
            // exact numpy op order: mul, mul, add (no FMA), then spike gate
            const float v = (w * xt) + (a * Vm);
            Vm = (Vm - 1.0f >= 0.0f) ? 0.0f : v;
            obuf[k * CCH + tid] = Vm;
        }
        sfence();
    };

    // Write burst: wave wv stores rows 4i+wv, one 1 KiB contiguous x4-instr
    // per row; block instruction i covers rows 4i..4i+3 = 4 KiB contiguous.
    auto stores = [&](int Wt) {
#pragma unroll
        for (int i = 0; i < 8; ++i) {
            const int r = 4 * i + wv;
            const f32x4 vv = *(const f32x4*)&obuf[r * CCH + 4 * l];
            *(f32x4*)(og + (size_t)(Wt * WIN + r) * CCH + 4 * l) = vv;
        }
        sfence();
    };

    auto lds_barrier = [&] {
        sfence();
        asm volatile("s_waitcnt lgkmcnt(0)" ::: "memory");
        __builtin_amdgcn_s_barrier();
        sfence();
    };

    // Prologue: x[0], x[1] in flight; x[0] complete before compute 0.
    issue(0); issue(1);
    asm volatile("s_waitcnt vmcnt(8)" ::: "memory");   // x[0] done (x[1] behind)
    __builtin_amdgcn_s_barrier();

    // W = 0: after L1: issue(2) 8 + stores(0) 8 = 16
    issue(2);
    compute(0);
    lds_barrier();
    stores(0);
    asm volatile("s_waitcnt vmcnt(16)" ::: "memory");  // x[1] done
    __builtin_amdgcn_s_barrier();

    // W = 1..13 steady: after L(W+1): stores(W-1) 8 + issue(W+2) 8 + stores(W) 8 = 24
    for (int W = 1; W <= NWIN - 3; ++W) {
        issue(W + 2);
        compute(W);
        lds_barrier();
        stores(W);
        asm volatile("s_waitcnt vmcnt(24)" ::: "memory");  // x[W+1] done
        __builtin_amdgcn_s_barrier();
    }

    // W = 14: no issue; after L15: stores(13) 8 + stores(14) 8 = 16
    compute(NWIN - 2);
    lds_barrier();
    stores(NWIN - 2);
    asm volatile("s_waitcnt vmcnt(16)" ::: "memory");  // x[15] done
    __builtin_amdgcn_s_barrier();

    // W = 15
    compute(NWIN - 1);
    lds_barrier();
    stores(NWIN - 1);
}

extern "C" void kernel_launch(void* const* d_in, const int* in_sizes, int n_in,
                              void* d_out, int out_size, void* d_ws, size_t ws_size,
                              hipStream_t stream) {
    const float* x       = (const float*)d_in[0];
    const float* w_input = (const float*)d_in[1];
    const float* w_leak  = (const float*)d_in[2];
    float* out = (float*)d_out;

    dim3 grid(NSEQ);        // 128 blocks, block n = sequence n
    dim3 block(CCH);        // 256 threads = 4 waves
    hipLaunchKernelGGL(lif_kernel, grid, block, 0, stream,
                       x, w_input, w_leak, out);
}